// Round 3
// baseline (215.168 us; speedup 1.0000x reference)
//
#include <hip/hip_runtime.h>
#include <stdint.h>

#define SIZE 65535

typedef __bf16 bf16x8 __attribute__((ext_vector_type(8)));
typedef float floatx4 __attribute__((ext_vector_type(4)));

// ws layout (bf16 elements), FRAGMENT-LINEAR: chunk = tile*64 + lane, 8 elems/chunk.
#define WS_ENCW 0        // [nt8][kt8][lane][8]        -> 32768
#define WS_WIH  32768    // [nt8][g3][kt4][lane][8]    -> 49152
#define WS_WHH  81920    // [nt8][g3][kt4][lane][8]    -> 49152
#define WS_VW   131072   // [nt4][kt4][lane][8]        -> 8192
#define WS_DECW 139264   // [kt8][lane][8] (rows>=10 and kt>=6 zero) -> 4096
#define WS_TOTC 17920    // total chunks (x8 elems = 143360)

__device__ __forceinline__ unsigned short f2bf(float f) {
    union { float f; unsigned int u; } v; v.f = f;
    unsigned int u = v.u;
    return (unsigned short)((u + 0x7fffu + ((u >> 16) & 1u)) >> 16);
}
__device__ __forceinline__ float bf2f(unsigned short b) {
    union { unsigned int u; float f; } v; v.u = ((unsigned int)b) << 16;
    return v.f;
}
__device__ __forceinline__ float sigmf(float x) {
    x = fminf(fmaxf(x, -30.f), 30.f);
    return 1.f / (1.f + __expf(-x));
}
__device__ __forceinline__ float tanhfast(float x) {
    x = fminf(fmaxf(x, -15.f), 15.f);
    float e = __expf(2.f * x);
    return (e - 1.f) / (e + 1.f);
}

union BF8 { bf16x8 v; unsigned short s[8]; };

__device__ __forceinline__ bf16x8 cvt8g(const float* p) {
    float4 a = *reinterpret_cast<const float4*>(p);
    float4 b = *reinterpret_cast<const float4*>(p + 4);
    BF8 r;
    r.s[0] = f2bf(a.x); r.s[1] = f2bf(a.y); r.s[2] = f2bf(a.z); r.s[3] = f2bf(a.w);
    r.s[4] = f2bf(b.x); r.s[5] = f2bf(b.y); r.s[6] = f2bf(b.z); r.s[7] = f2bf(b.w);
    return r.v;
}
__device__ __forceinline__ bf16x8 ld8(const unsigned short* p) {
    return *reinterpret_cast<const bf16x8*>(p);
}

// async global->LDS, 16B per lane, no VGPR destination; tracked by vmcnt.
__device__ __forceinline__ void glds16(const unsigned short* g, unsigned short* l) {
    __builtin_amdgcn_global_load_lds(
        (const __attribute__((address_space(1))) unsigned int*)g,
        (__attribute__((address_space(3))) unsigned int*)l, 16, 0, 0);
}

// All chunks are 8 fragments (8KB); every thread issues EXACTLY 2 glds16.
// This uniformity is what makes the counted vmcnt(N) constants exact.
__device__ __forceinline__ void stage_seq8(unsigned short* dst, const unsigned short* src,
                                           int wave, int lane) {
    glds16(src + (size_t)wave * 512 + lane * 8, dst + wave * 512);
    glds16(src + (size_t)(wave + 4) * 512 + lane * 8, dst + (wave + 4) * 512);
}
__device__ __forceinline__ void stage_gru(unsigned short* dst, const unsigned short* wsw,
                                          int ng, int wave, int lane) {
    const int fo = (ng * 4 + wave) * 512 + lane * 8;
    glds16(wsw + WS_WIH + fo, dst + wave * 512);
    glds16(wsw + WS_WHH + fo, dst + (4 + wave) * 512);
}
// chunk schedule: 0..7 enc | 8..31 gru(ng=i-8) | 32,33 v_w halves | 34 dec
__device__ __forceinline__ void stage_chunk(int i, unsigned short (*wbuf)[4096],
                                            const unsigned short* wsw, int wave, int lane) {
    unsigned short* dst = wbuf[i & 3];
    if (i < 8)       stage_seq8(dst, wsw + WS_ENCW + i * 4096, wave, lane);
    else if (i < 32) stage_gru(dst, wsw, i - 8, wave, lane);
    else if (i < 34) stage_seq8(dst, wsw + WS_VW + (i - 32) * 4096, wave, lane);
    else             stage_seq8(dst, wsw + WS_DECW, wave, lane);
}

#define WAITVM(N) asm volatile("s_waitcnt vmcnt(" #N ")" ::: "memory")
#define BARRIER() do { __builtin_amdgcn_s_barrier(); __builtin_amdgcn_sched_barrier(0); } while (0)
#define SCHEDFENCE() __builtin_amdgcn_sched_barrier(0)

// ---------- pre-kernel: f32 weights -> bf16 fragment-linear layout ----------
__global__ __launch_bounds__(256) void cvt_weights(
    const float* __restrict__ enc_w, const float* __restrict__ w_ih,
    const float* __restrict__ w_hh, const float* __restrict__ v_w,
    const float* __restrict__ dec_w, unsigned short* __restrict__ ws) {
    int c = blockIdx.x * 256 + threadIdx.x;
    if (c >= WS_TOTC) return;
    const int lane = c & 63;
    const int l = lane & 15;
    const int q = lane >> 4;
    const float* src; int row, col, stride; bool zero = false;
    if (c < 4096) {                      // enc_w [nt8][kt8]
        int lt = c >> 6; int nt = lt >> 3, kt = lt & 7;
        row = nt * 16 + l; col = kt * 32 + q * 8; src = enc_w; stride = 256;
    } else if (c < 10240) {              // w_ih [nt8][g3][kt4]
        int lt = (c - 4096) >> 6; int nt = lt / 12; int r2 = lt % 12;
        int g = r2 >> 2, kt = r2 & 3;
        row = g * 128 + nt * 16 + l; col = kt * 32 + q * 8; src = w_ih; stride = 128;
    } else if (c < 16384) {              // w_hh
        int lt = (c - 10240) >> 6; int nt = lt / 12; int r2 = lt % 12;
        int g = r2 >> 2, kt = r2 & 3;
        row = g * 128 + nt * 16 + l; col = kt * 32 + q * 8; src = w_hh; stride = 128;
    } else if (c < 17408) {              // v_w [nt4][kt4]
        int lt = (c - 16384) >> 6; int nt = lt >> 2, kt = lt & 3;
        row = nt * 16 + l; col = kt * 32 + q * 8; src = v_w; stride = 128;
    } else {                             // dec_w [kt8], zero rows>=10 / kt>=6
        int kt = (c - 17408) >> 6;
        row = l; col = kt * 32 + q * 8; src = dec_w; stride = 192;
        zero = (l >= 10) || (kt >= 6);
    }
    float4 a, b;
    if (zero) { a = make_float4(0.f,0.f,0.f,0.f); b = a; }
    else {
        const float* p = src + (size_t)row * stride + col;
        a = *reinterpret_cast<const float4*>(p);
        b = *reinterpret_cast<const float4*>(p + 4);
    }
    unsigned short* d = ws + (size_t)c * 8;
    d[0]=f2bf(a.x); d[1]=f2bf(a.y); d[2]=f2bf(a.z); d[3]=f2bf(a.w);
    d[4]=f2bf(b.x); d[5]=f2bf(b.y); d[6]=f2bf(b.z); d[7]=f2bf(b.w);
}

// ---------- main fused kernel ----------
// Counted-vmcnt weight pipeline (T3+T4): ring of 4x8KB chunk buffers, 3 chunks
// in flight, raw s_barrier + s_waitcnt vmcnt(N) (NEVER 0 in the loop). Chunk
// loads are uniform 2/thread; GRU hprev loads (8/nt) are pinned before the
// wait -> vmcnt(12) exact there, vmcnt(4) elsewhere, conservative tail waits.
// Biases live in LDS (no stray VMEM in the counted stream). sV/sO overlay the
// dead sA region -> LDS 71.5KB, 2 blocks/CU.
__global__ __launch_bounds__(256, 2) void attn_critic_kernel(
    const float* __restrict__ obs,    // [SIZE,256] f32
    const float* __restrict__ hid,    // [SIZE,128] f32
    const float* __restrict__ enc_b,  // [128] f32
    const float* __restrict__ b_ih,   // [384] f32
    const float* __restrict__ b_hh,   // [384] f32
    const float* __restrict__ v_b,    // [64] f32
    const float* __restrict__ dec_b,  // [10] f32
    const unsigned short* __restrict__ wsw,  // bf16 fragment-linear weights
    float* __restrict__ out)          // [SIZE*10] ++ [SIZE*128] f32
{
    __shared__ __align__(16) unsigned short wbuf[4][4096];   // 32 KB ring
    __shared__ __align__(16) unsigned short pool[4][4352];   // 34.8 KB: sA, later sV+sO
    __shared__ __align__(16) float sBias[976];               // 3.9 KB

    const int tid  = threadIdx.x;
    const int wave = tid >> 6;
    const int lane = tid & 63;
    const int l15  = lane & 15;
    const int quad = lane >> 4;
    const int wrow0 = (blockIdx.x * 4 + wave) * 32;

    unsigned short (*sA)[136] = (unsigned short(*)[136])&pool[wave][0];  // [32][136]
    unsigned short (*sV)[72]  = (unsigned short(*)[72]) &pool[wave][0];  // [32][72] overlay
    float* sO = (float*)&pool[wave][2304];                               // [32][10] overlay

    int rA0 = wrow0 + l15;      rA0 = (rA0 < SIZE) ? rA0 : (SIZE - 1);
    int rA1 = wrow0 + 16 + l15; rA1 = (rA1 < SIZE) ? rA1 : (SIZE - 1);

    // ---- prologue: stage chunks 0..2, biases->LDS, prefetch A-fragments ----
    stage_chunk(0, wbuf, wsw, wave, lane);
    stage_chunk(1, wbuf, wsw, wave, lane);
    stage_chunk(2, wbuf, wsw, wave, lane);
    SCHEDFENCE();

    // biases: [0..127]=enc_b [128..511]=b_ih [512..895]=b_hh [896..959]=v_b [960..969]=dec_b
    for (int i = tid; i < 970; i += 256) {
        float v;
        if (i < 128)      v = enc_b[i];
        else if (i < 512) v = b_ih[i - 128];
        else if (i < 896) v = b_hh[i - 512];
        else if (i < 960) v = v_b[i - 896];
        else              v = dec_b[i - 960];
        sBias[i] = v;
    }

    bf16x8 aob[2][8], hf[2][4];
    {
        const float* o0 = obs + (size_t)rA0 * 256;
        const float* o1 = obs + (size_t)rA1 * 256;
#pragma unroll
        for (int kt = 0; kt < 8; ++kt) {
            aob[0][kt] = cvt8g(o0 + kt * 32 + quad * 8);
            aob[1][kt] = cvt8g(o1 + kt * 32 + quad * 8);
        }
        const float* h0 = hid + (size_t)rA0 * 128;
        const float* h1 = hid + (size_t)rA1 * 128;
#pragma unroll
        for (int kt = 0; kt < 4; ++kt) {
            hf[0][kt] = cvt8g(h0 + kt * 32 + quad * 8);
            hf[1][kt] = cvt8g(h1 + kt * 32 + quad * 8);
        }
    }
    asm volatile("s_waitcnt lgkmcnt(0)" ::: "memory");   // bias ds_writes done
    SCHEDFENCE();

    // ---- Phase 1: X = relu(OBS @ enc_w^T + enc_b), chunks 0..7 ----
#pragma unroll 1
    for (int nt = 0; nt < 8; ++nt) {
        WAITVM(4);            // chunk nt staged (>=4 ops always follow it)
        BARRIER();
        stage_chunk(nt + 3, wbuf, wsw, wave, lane);
        SCHEDFENCE();
        const unsigned short* wb = wbuf[nt & 3];
        const float bias = sBias[nt * 16 + l15];
        floatx4 a0 = floatx4{0.f,0.f,0.f,0.f}, a1 = a0;
#pragma unroll
        for (int kt = 0; kt < 8; ++kt) {
            bf16x8 b = ld8(&wb[kt * 512 + lane * 8]);
            a0 = __builtin_amdgcn_mfma_f32_16x16x32_bf16(aob[0][kt], b, a0, 0, 0, 0);
            a1 = __builtin_amdgcn_mfma_f32_16x16x32_bf16(aob[1][kt], b, a1, 0, 0, 0);
        }
#pragma unroll
        for (int r = 0; r < 4; ++r) {
            sA[quad * 4 + r][nt * 16 + l15]      = f2bf(fmaxf(a0[r] + bias, 0.f));
            sA[16 + quad * 4 + r][nt * 16 + l15] = f2bf(fmaxf(a1[r] + bias, 0.f));
        }
    }

    bf16x8 xf[2][4];
#pragma unroll
    for (int kt = 0; kt < 4; ++kt) {
        xf[0][kt] = ld8(&sA[l15][kt * 32 + quad * 8]);
        xf[1][kt] = ld8(&sA[16 + l15][kt * 32 + quad * 8]);
    }

    // ---- Phase 2: GRU cell, chunks 8..31 (nt*3+g) ----
#pragma unroll 1
    for (int nt = 0; nt < 8; ++nt) {
        const int nr = nt * 16 + l15;
        const int c0 = 8 + nt * 3;
        // hprev: exactly 8 dword loads, issued BEFORE the wait -> in the count
        float hp[2][4];
#pragma unroll
        for (int m = 0; m < 2; ++m)
#pragma unroll
            for (int r = 0; r < 4; ++r) {
                const int grow = wrow0 + m * 16 + quad * 4 + r;
                const int rowc = (grow < SIZE) ? grow : (SIZE - 1);
                hp[m][r] = hid[(size_t)rowc * 128 + nr];
            }
        const float bir_ = sBias[128 + nr], biz_ = sBias[256 + nr], bin_ = sBias[384 + nr];
        const float bhr_ = sBias[512 + nr], bhz_ = sBias[640 + nr], bhn_ = sBias[768 + nr];
        floatx4 gi[3][2], gh[3][2];
#pragma unroll
        for (int g = 0; g < 3; ++g) {
            gi[g][0] = floatx4{0.f,0.f,0.f,0.f}; gi[g][1] = gi[g][0];
            gh[g][0] = gi[g][0]; gh[g][1] = gi[g][0];
        }
#pragma unroll
        for (int g = 0; g < 3; ++g) {
            // outstanding before wait: chunk c(2), c+1(2), c+2(2), hp(8) -> after-c = 12
            WAITVM(12);
            BARRIER();
            stage_chunk(c0 + g + 3, wbuf, wsw, wave, lane);
            SCHEDFENCE();
            const unsigned short* wb = wbuf[(c0 + g) & 3];
#pragma unroll
            for (int kt = 0; kt < 4; ++kt) {
                bf16x8 bi = ld8(&wb[kt * 512 + lane * 8]);
                bf16x8 bh = ld8(&wb[(4 + kt) * 512 + lane * 8]);
                gi[g][0] = __builtin_amdgcn_mfma_f32_16x16x32_bf16(xf[0][kt], bi, gi[g][0], 0, 0, 0);
                gi[g][1] = __builtin_amdgcn_mfma_f32_16x16x32_bf16(xf[1][kt], bi, gi[g][1], 0, 0, 0);
                gh[g][0] = __builtin_amdgcn_mfma_f32_16x16x32_bf16(hf[0][kt], bh, gh[g][0], 0, 0, 0);
                gh[g][1] = __builtin_amdgcn_mfma_f32_16x16x32_bf16(hf[1][kt], bh, gh[g][1], 0, 0, 0);
            }
        }
#pragma unroll
        for (int m = 0; m < 2; ++m)
#pragma unroll
            for (int r = 0; r < 4; ++r) {
                float rg = sigmf(gi[0][m][r] + bir_ + gh[0][m][r] + bhr_);
                float zg = sigmf(gi[1][m][r] + biz_ + gh[1][m][r] + bhz_);
                float ng2 = tanhfast(gi[2][m][r] + bin_ + rg * (gh[2][m][r] + bhn_));
                float ho = (1.f - zg) * ng2 + zg * hp[m][r];
                sA[m * 16 + quad * 4 + r][nr] = f2bf(ho);
            }
    }

    // ---- capture h_out fragments, then store h_out (before sV overlays sA) ----
    bf16x8 af[2][4];
#pragma unroll
    for (int kt = 0; kt < 4; ++kt) {
        af[0][kt] = ld8(&sA[l15][kt * 32 + quad * 8]);
        af[1][kt] = ld8(&sA[16 + l15][kt * 32 + quad * 8]);
    }
    {
        float* out_h = out + (size_t)SIZE * 10;
#pragma unroll 1
        for (int it = 0; it < 16; ++it) {
            int idx = it * 256 + lane * 4;   // over [32][128]
            int rr = idx >> 7, cc = idx & 127;
            int grow = wrow0 + rr;
            if (grow < SIZE) {
                float2 p0 = make_float2(bf2f(sA[rr][cc]),     bf2f(sA[rr][cc + 1]));
                float2 p1 = make_float2(bf2f(sA[rr][cc + 2]), bf2f(sA[rr][cc + 3]));
                float* dst = out_h + (size_t)grow * 128 + cc;
                *reinterpret_cast<float2*>(dst)     = p0;
                *reinterpret_cast<float2*>(dst + 2) = p1;
            }
        }
    }

    // ---- Phase 3: V = relu(H_OUT @ v_w^T + v_b), chunks 32,33 ----
    // Tail waits: conservative WAITVM(4). At the first one, >=16 h_out stores are
    // the newest ops, so leaving 4 outstanding retires all staging loads. Safe
    // regardless of how the compiler merges the stores.
#pragma unroll
    for (int ci = 0; ci < 2; ++ci) {
        WAITVM(4);
        BARRIER();
        const unsigned short* wb = wbuf[(32 + ci) & 3];
#pragma unroll
        for (int ntl = 0; ntl < 2; ++ntl) {
            const int nt = ci * 2 + ntl;
            const float bias = sBias[896 + nt * 16 + l15];
            floatx4 a0 = floatx4{0.f,0.f,0.f,0.f}, a1 = a0;
#pragma unroll
            for (int kt = 0; kt < 4; ++kt) {
                bf16x8 b = ld8(&wb[(ntl * 4 + kt) * 512 + lane * 8]);
                a0 = __builtin_amdgcn_mfma_f32_16x16x32_bf16(af[0][kt], b, a0, 0, 0, 0);
                a1 = __builtin_amdgcn_mfma_f32_16x16x32_bf16(af[1][kt], b, a1, 0, 0, 0);
            }
#pragma unroll
            for (int r = 0; r < 4; ++r) {
                sV[quad * 4 + r][nt * 16 + l15]      = f2bf(fmaxf(a0[r] + bias, 0.f));
                sV[16 + quad * 4 + r][nt * 16 + l15] = f2bf(fmaxf(a1[r] + bias, 0.f));
            }
        }
    }

    // ---- Phase 4: OUT = [H_OUT|V] @ dec_w^T + dec_b, chunk 34 ----
    {
        WAITVM(4);
        BARRIER();
        const unsigned short* wb = wbuf[34 & 3];
        floatx4 d0 = floatx4{0.f,0.f,0.f,0.f}, d1 = d0;
#pragma unroll
        for (int kt = 0; kt < 6; ++kt) {
            bf16x8 b = ld8(&wb[kt * 512 + lane * 8]);
            bf16x8 a0 = (kt < 4) ? af[0][kt] : ld8(&sV[l15][(kt - 4) * 32 + quad * 8]);
            bf16x8 a1 = (kt < 4) ? af[1][kt] : ld8(&sV[16 + l15][(kt - 4) * 32 + quad * 8]);
            d0 = __builtin_amdgcn_mfma_f32_16x16x32_bf16(a0, b, d0, 0, 0, 0);
            d1 = __builtin_amdgcn_mfma_f32_16x16x32_bf16(a1, b, d1, 0, 0, 0);
        }
        if (l15 < 10) {
            const float bias = sBias[960 + l15];
#pragma unroll
            for (int r = 0; r < 4; ++r) {
                sO[(quad * 4 + r) * 10 + l15]      = d0[r] + bias;
                sO[(16 + quad * 4 + r) * 10 + l15] = d1[r] + bias;
            }
        }
        // coalesced store: 320 consecutive f32 per wave
#pragma unroll
        for (int j = 0; j < 5; ++j) {
            int idx = j * 64 + lane;          // 0..319
            int row = idx / 10, col = idx % 10;
            int grow = wrow0 + row;
            if (grow < SIZE)
                out[(size_t)grow * 10 + col] = sO[row * 10 + col];
        }
    }
}

extern "C" void kernel_launch(void* const* d_in, const int* in_sizes, int n_in,
                              void* d_out, int out_size, void* d_ws, size_t ws_size,
                              hipStream_t stream) {
    const float* obs   = (const float*)d_in[0];
    const float* hid   = (const float*)d_in[1];
    const float* enc_w = (const float*)d_in[2];
    const float* enc_b = (const float*)d_in[3];
    const float* w_ih  = (const float*)d_in[4];
    const float* w_hh  = (const float*)d_in[5];
    const float* b_ih  = (const float*)d_in[6];
    const float* b_hh  = (const float*)d_in[7];
    // d_in[8..19]: dead code (bi-GRU / hard attention / q,k) — unused.
    const float* v_w   = (const float*)d_in[20];
    const float* v_b   = (const float*)d_in[21];
    const float* dec_w = (const float*)d_in[22];
    const float* dec_b = (const float*)d_in[23];
    unsigned short* wsw = (unsigned short*)d_ws;
    float* out = (float*)d_out;

    hipLaunchKernelGGL(cvt_weights, dim3((WS_TOTC + 255) / 256), dim3(256), 0, stream,
                       enc_w, w_ih, w_hh, v_w, dec_w, wsw);
    // 512 blocks x 4 waves x 32 rows = 65536 >= 65535; 2 blocks/CU resident
    hipLaunchKernelGGL(attn_critic_kernel, dim3(512), dim3(256), 0, stream,
                       obs, hid, enc_b, b_ih, b_hh, v_b, dec_b, wsw, out);
}